// Round 4
// baseline (60.529 us; speedup 1.0000x reference)
//
#include <hip/hip_runtime.h>
#include <math.h>

#define NB 128
#define NR 36
#define NT 128
#define ND 1024
#define TTA 32      // tokens per scores-block
#define CK 256      // K chunk
#define LST 264     // LDS f16 row stride (528 B)
#define WST 64      // w row stride in ws (f16), cols 36..63 = 0

typedef float    f32x4 __attribute__((ext_vector_type(4)));
typedef _Float16 f16x8 __attribute__((ext_vector_type(8)));
typedef _Float16 f16x4 __attribute__((ext_vector_type(4)));

// ============ Kernel A: cosine scores + softmax over regions -> w (f16) ============
__global__ __launch_bounds__(256, 3)
void scores_softmax(const float* __restrict__ img, const float* __restrict__ cap,
                    _Float16* __restrict__ w_ws) {
    __shared__ __align__(16) _Float16 img_c[48][LST];   // 25344 B (rows 36..47 garbage, cols ignored)
    __shared__ __align__(16) _Float16 cap_c[TTA][LST];  // 16896 B
    __shared__ float sc_s[TTA][52];                     //  6656 B
    __shared__ float ni_s[NR];
    __shared__ float nc_s[TTA];

    const int tid  = threadIdx.x;
    const int phys = blockIdx.x;
    // XCD swizzle: XCD x owns batches [x*16, x*16+16) (matches kernel B)
    const int lb = (phys & 7) * 64 + (phys >> 3);
    const int b  = lb >> 2;
    const int t0 = (lb & 3) * TTA;

    const float* imgB = img + (size_t)b * NR * ND;
    const float* capB = cap + ((size_t)b * NT + t0) * ND;

    const int wv = tid >> 6, lane = tid & 63, ln = lane & 15, hi = lane >> 4;
    const int khalf = wv >> 1;     // K-half of each chunk (128)
    const int mf    = wv & 1;      // token fragment

    // zero-init score accumulator (guarded by first loop barrier)
    for (int i = tid; i < TTA * 52; i += 256) ((float*)sc_s)[i] = 0.f;

    float nip[9], ncp[8];
    #pragma unroll
    for (int i = 0; i < 9; ++i) nip[i] = 0.f;
    #pragma unroll
    for (int i = 0; i < 8; ++i) ncp[i] = 0.f;
    f32x4 acc[3] = {{0.f,0.f,0.f,0.f},{0.f,0.f,0.f,0.f},{0.f,0.f,0.f,0.f}};

    for (int kc = 0; kc < ND; kc += CK) {
        __syncthreads();   // previous chunk's readers done (and sc_s init visible)
        // stage img 36 x 256 f32 -> f16, accumulate norm partials
        #pragma unroll
        for (int i = 0; i < 9; ++i) {
            const int f = tid + 256 * i;          // wave-aligned: row uniform per wave
            const int r = f >> 6, c4 = f & 63;
            const float4 v = *(const float4*)(imgB + r * ND + kc + c4 * 4);
            nip[i] = fmaf(v.x, v.x, fmaf(v.y, v.y, fmaf(v.z, v.z, fmaf(v.w, v.w, nip[i]))));
            f16x4 h; h[0] = (_Float16)v.x; h[1] = (_Float16)v.y;
                     h[2] = (_Float16)v.z; h[3] = (_Float16)v.w;
            *(f16x4*)(&img_c[r][c4 * 4]) = h;
        }
        // stage cap 32 x 256
        #pragma unroll
        for (int i = 0; i < 8; ++i) {
            const int f = tid + 256 * i;
            const int t = f >> 6, c4 = f & 63;
            const float4 v = *(const float4*)(capB + t * ND + kc + c4 * 4);
            ncp[i] = fmaf(v.x, v.x, fmaf(v.y, v.y, fmaf(v.z, v.z, fmaf(v.w, v.w, ncp[i]))));
            f16x4 h; h[0] = (_Float16)v.x; h[1] = (_Float16)v.y;
                     h[2] = (_Float16)v.z; h[3] = (_Float16)v.w;
            *(f16x4*)(&cap_c[t][c4 * 4]) = h;
        }
        __syncthreads();
        // MFMA: D[m=token][n=region], this wave: m=mf, K range [khalf*128, +128)
        #pragma unroll
        for (int ks = 0; ks < 4; ++ks) {
            const int ko = khalf * 128 + ks * 32 + hi * 8;
            const f16x8 a = *(const f16x8*)(&cap_c[mf * 16 + ln][ko]);
            #pragma unroll
            for (int nf = 0; nf < 3; ++nf) {
                const f16x8 bb = *(const f16x8*)(&img_c[nf * 16 + ln][ko]);
                acc[nf] = __builtin_amdgcn_mfma_f32_16x16x32_f16(a, bb, acc[nf], 0, 0, 0);
            }
        }
    }

    // combine K-halves (C/D layout: col=lane&15 -> region, row=(lane>>4)*4+reg -> token)
    const int tb = mf * 16 + hi * 4;
    #pragma unroll
    for (int nf = 0; nf < 3; ++nf)
        #pragma unroll
        for (int j = 0; j < 4; ++j)
            atomicAdd(&sc_s[tb + j][nf * 16 + ln], acc[nf][j]);

    // norms: wave wv exclusively owns img rows {wv+4i} and cap rows {wv+4i}
    #pragma unroll
    for (int i = 0; i < 9; ++i) {
        float s = nip[i];
        #pragma unroll
        for (int off = 32; off; off >>= 1) s += __shfl_xor(s, off, 64);
        if (lane == 0) ni_s[wv + 4 * i] = sqrtf(s);
    }
    #pragma unroll
    for (int i = 0; i < 8; ++i) {
        float s = ncp[i];
        #pragma unroll
        for (int off = 32; off; off >>= 1) s += __shfl_xor(s, off, 64);
        if (lane == 0) nc_s[wv + 4 * i] = sqrtf(s);
    }
    __syncthreads();

    // softmax over regions, one thread per token; write w (f16, cols 36..63 = 0)
    if (tid < TTA) {
        const float nct = nc_s[tid];
        float v[NR];
        float m = -1e30f;
        #pragma unroll
        for (int r = 0; r < NR; ++r) {
            const float d = fmaxf(ni_s[r] * nct, 1e-8f);
            v[r] = sc_s[tid][r] / d;
            m = fmaxf(m, v[r]);
        }
        float sum = 0.f;
        #pragma unroll
        for (int r = 0; r < NR; ++r) { v[r] = __expf(v[r] - m); sum += v[r]; }
        const float inv = 1.f / sum;
        _Float16* wO = w_ws + (size_t)(b * NT + t0 + tid) * WST;
        #pragma unroll
        for (int q = 0; q < 8; ++q) {
            f16x8 h;
            #pragma unroll
            for (int j = 0; j < 8; ++j) {
                const int r = q * 8 + j;
                h[j] = (r < NR) ? (_Float16)(v[r] * inv) : (_Float16)0.f;
            }
            *(f16x8*)(wO + q * 8) = h;
        }
    }
}

// ============ Kernel B: out[t][d] = sum_r w[t][r] * img[r][d] via MFMA ============
__global__ __launch_bounds__(256, 4)
void pool_mfma(const float* __restrict__ img, const _Float16* __restrict__ w_ws,
               float* __restrict__ out) {
    const int tid  = threadIdx.x;
    const int phys = blockIdx.x;
    const int lb = (phys & 7) * 256 + (phys >> 3);   // same XCD->batch mapping as kernel A
    const int b  = lb >> 4;
    const int tq = (lb >> 2) & 3;
    const int dq = lb & 3;
    const int t0 = tq * 32;

    const int wv = tid >> 6, lane = tid & 63, ln = lane & 15, hi = lane >> 4;
    const int dw = dq * 256 + wv * 64;               // this wave's d-base (64 wide)

    const float*    imgB = img  + (size_t)b * NR * ND;
    const _Float16* wB   = w_ws + (size_t)(b * NT + t0) * WST;
    float*          outB = out  + ((size_t)(b * NT + t0)) * ND;

    // A-frags (w): A[m=t][k=r]; lane: m = mfrag*16+ln, k = kk*32 + hi*8 + j
    f16x8 afr[2][2];
    #pragma unroll
    for (int mfr = 0; mfr < 2; ++mfr)
        #pragma unroll
        for (int kk = 0; kk < 2; ++kk)
            afr[mfr][kk] = *(const f16x8*)(wB + (mfr * 16 + ln) * WST + kk * 32 + hi * 8);

    f32x4 acc[2][4];
    #pragma unroll
    for (int mfr = 0; mfr < 2; ++mfr)
        #pragma unroll
        for (int nf = 0; nf < 4; ++nf)
            acc[mfr][nf] = (f32x4){0.f, 0.f, 0.f, 0.f};

    #pragma unroll
    for (int nf = 0; nf < 4; ++nf) {
        const int dcol = dw + nf * 16 + ln;
        #pragma unroll
        for (int kk = 0; kk < 2; ++kk) {
            // B-frag (img): B[k=r][n=d]; r >= 36 clamped (w cols are zero there)
            f16x8 bfr;
            #pragma unroll
            for (int j = 0; j < 8; ++j) {
                int r = kk * 32 + hi * 8 + j;
                if (r >= NR) r = NR - 1;             // safe addr; killed by w==0
                bfr[j] = (_Float16)imgB[r * ND + dcol];
            }
            #pragma unroll
            for (int mfr = 0; mfr < 2; ++mfr)
                acc[mfr][nf] = __builtin_amdgcn_mfma_f32_16x16x32_f16(afr[mfr][kk], bfr, acc[mfr][nf], 0, 0, 0);
        }
    }

    // store: D row = mfr*16 + hi*4 + j (token), col = nf*16 + ln (d)
    #pragma unroll
    for (int mfr = 0; mfr < 2; ++mfr)
        #pragma unroll
        for (int nf = 0; nf < 4; ++nf)
            #pragma unroll
            for (int j = 0; j < 4; ++j)
                outB[(size_t)(mfr * 16 + hi * 4 + j) * ND + dw + nf * 16 + ln] = acc[mfr][nf][j];
}

extern "C" void kernel_launch(void* const* d_in, const int* in_sizes, int n_in,
                              void* d_out, int out_size, void* d_ws, size_t ws_size,
                              hipStream_t stream) {
    const float* img = (const float*)d_in[0];   // [B, R, D]
    const float* cap = (const float*)d_in[1];   // [B, T, D]
    float* out = (float*)d_out;                 // [B, T, D]
    _Float16* w_ws = (_Float16*)d_ws;           // [B, T, 64] f16 = 2.0 MB

    scores_softmax<<<NB * 4, 256, 0, stream>>>(img, cap, w_ws);
    pool_mfma<<<NB * 16, 256, 0, stream>>>(img, w_ws, out);
}